// Round 9
// baseline (915.546 us; speedup 1.0000x reference)
//
#include <hip/hip_runtime.h>
#include <stdint.h>

#define NN 20000
#define DD 16
#define FF 128
#define GG 512   // 4*F

typedef _Float16 h16;
typedef _Float16 half8 __attribute__((ext_vector_type(8)));
typedef float f32x4 __attribute__((ext_vector_type(4)));
typedef float f32x16 __attribute__((ext_vector_type(16)));

// ---- workspace layout (bytes, all 256-aligned) ----
#define OFF_X    0u          // x_f16   [N][128]          5,120,000
#define OFF_H1   5120000u    // h1_f16  [N][128]          5,120,000
#define OFF_N1   10240000u   // n1buf   [2][N][128] f16  10,240,000
#define OFF_N2   20480000u   // n2buf   [2][N][128] f16  10,240,000
#define OFF_B1   30720000u   // Bpack   [4sets][16w][16kc][64lane][8] f16 (1MB)
#define OFF_WC1  31768576u   // Cpack   [12][8][64][8] f16
#define OFF_WC2  31866880u   // Wcat2   [384][2] f32
#define OFF_BI1  31869952u   // bias1   [2][512] f32
#define OFF_BI2  31874048u   // bias2   [2][512] f32
#define OFF_BS1  31878144u   // bs1     [128] f32
#define OFF_B2S  31878656u   // b2s     [2] f32
#define OFF_PERM 31878912u   // perm    [2][N] int32       160,000
#define OFF_HIST 32039168u   // hist    [2][32] int32
#define OFF_CUR  32039424u   // cursor  [2][32] int32

__device__ __forceinline__ float sigm(float x)  { return __builtin_amdgcn_rcpf(1.f + __expf(-x)); }
__device__ __forceinline__ float tanh_(float x) { return 2.f * __builtin_amdgcn_rcpf(1.f + __expf(-2.f * x)) - 1.f; }

// raw barrier: LDS ops visible, but in-flight global loads (vmcnt) NOT drained
#define BAR() asm volatile("s_waitcnt lgkmcnt(0)\n\ts_barrier" ::: "memory")

// 16x16x32 A-fragment loader (k_lout1 only), [64][128] tile, (row&7)<<4 swizzle
__device__ __forceinline__ half8 load_afrag16(const unsigned short* Asrc, int rowbase,
                                              int ll, int lg, int kcL) {
    int row = rowbase + ll;
    int o = (kcL * 64 + lg * 16) ^ ((row & 7) << 4);
    return *(const half8*)((const char*)Asrc + row * 256 + o);
}

// ---------------- fused prep kernel ----------------
// grid 1696 x 256: [0,1250) cast_x | [1250,1506) pack_gates | [1506,1530) pack_wc1
// | [1530,1538) small (biases, wc2) | [1538,1696) degree histogram
// (hist zeroed by hipMemsetAsync before this kernel)
__global__ void k_prep(const float* __restrict__ x, h16* __restrict__ xo,
                       const float* __restrict__ l1Wih, const float* __restrict__ l1Whh,
                       const float* __restrict__ l2Wih, const float* __restrict__ l2Whh,
                       h16* __restrict__ Bp,
                       const float* __restrict__ l1Ws, const float* __restrict__ l1Wn,
                       h16* __restrict__ Cp,
                       const float* __restrict__ l1bih, const float* __restrict__ l1bhh,
                       const float* __restrict__ l2bih, const float* __restrict__ l2bhh,
                       const float* __restrict__ l1b,  const float* __restrict__ l2Ws,
                       const float* __restrict__ l2Wn, const float* __restrict__ l2b,
                       float* __restrict__ bias1, float* __restrict__ bias2,
                       float* __restrict__ bs1,  float* __restrict__ wc2,
                       float* __restrict__ b2s,
                       const int* __restrict__ deg, int* __restrict__ hist) {
    const int b = blockIdx.x, tid = threadIdx.x;
    if (b < 1250) {
        int base = (b * 256 + tid) * 8;
        const float4* p = (const float4*)(x + base);
        float4 a = p[0], c = p[1];
        half8 v = {(h16)a.x,(h16)a.y,(h16)a.z,(h16)a.w,(h16)c.x,(h16)c.y,(h16)c.z,(h16)c.w};
        *(half8*)(xo + base) = v;
    } else if (b < 1506) {
        int idx = (b - 1250) * 256 + tid;
        int set = idx >> 14;
        int rem = idx & 16383;
        int w   = rem >> 10;
        int kc  = (rem >> 6) & 15;
        int l   = rem & 63;
        const float* Wih = (set < 2 ? l1Wih : l2Wih) + (size_t)(set & 1) * (FF * GG);
        const float* Whh = (set < 2 ? l1Whh : l2Whh) + (size_t)(set & 1) * (FF * GG);
        int rl   = l & 31;
        int gate = rl >> 3, fl = rl & 7;
        int col  = gate * 128 + w * 8 + fl;
        int hi   = l >> 5;
        half8 v;
#pragma unroll
        for (int j = 0; j < 8; j++) {
            int k = kc * 16 + 8 * hi + j;
            float val = (k < FF) ? Wih[k * GG + col] : Whh[(k - FF) * GG + col];
            v[j] = (h16)val;
        }
        *(half8*)(Bp + (size_t)idx * 8) = v;
    } else if (b < 1530) {
        int idx = (b - 1506) * 256 + tid;
        int kc = idx >> 9;
        int ct = (idx >> 6) & 7;
        int l  = idx & 63;
        int col = ct * 16 + (l & 15);
        half8 v;
#pragma unroll
        for (int j = 0; j < 8; j++) {
            int k = kc * 32 + ((l >> 4) << 3) + j;
            float val;
            if (k < 128)      val = 0.5f * (l1Ws[k * 128 + col] + l1Ws[16384 + k * 128 + col]);
            else if (k < 256) val = 0.5f * l1Wn[(k - 128) * 128 + col];
            else              val = 0.5f * l1Wn[16384 + (k - 256) * 128 + col];
            v[j] = (h16)val;
        }
        *(half8*)(Cp + (size_t)idx * 8) = v;
    } else if (b < 1538) {
        int g = (b - 1530) * 256 + tid;
        if (g < 1024) bias1[g] = l1bih[g] + l1bhh[g];
        else if (g < 2048) { int j = g - 1024; bias2[j] = l2bih[j] + l2bhh[j]; }
        if (g < 128) bs1[g] = 0.5f * (l1b[g] + l1b[128 + g]);
        if (g < 768) {
            int k = g >> 1, c = g & 1;
            float val;
            if (k < 128)      val = 0.5f * (l2Ws[k * 2 + c] + l2Ws[256 + k * 2 + c]);
            else if (k < 256) val = 0.5f * l2Wn[(k - 128) * 2 + c];
            else              val = 0.5f * l2Wn[256 + (k - 256) * 2 + c];
            wc2[g] = val;
        }
        if (g < 2) b2s[g] = 0.5f * (l2b[g] + l2b[2 + g]);
    } else {
        int bb = b - 1538;               // 0..157, 79 blocks per e
        int e = bb / 79;
        int n = (bb % 79) * 256 + tid;
        if (n < NN) atomicAdd(&hist[e * 32 + deg[(size_t)e * NN + n]], 1);
    }
}

// ---------------- degree sort (descending, counting sort) ----------------
__global__ void k_scan(const int* __restrict__ hist, int* __restrict__ cursor) {
    int e = threadIdx.x;
    if (e < 2) {
        int acc = 0;
        for (int d = 16; d >= 0; d--) { cursor[e * 32 + d] = acc; acc += hist[e * 32 + d]; }
    }
}
__global__ void k_scatter(const int* __restrict__ deg, int* __restrict__ cursor,
                          int* __restrict__ perm) {
    int e = blockIdx.y; int n = blockIdx.x * 256 + threadIdx.x;
    if (n < NN) {
        int d = deg[(size_t)e * NN + n];
        int p = atomicAdd(&cursor[e * 32 + d], 1);
        perm[(size_t)e * NN + p] = n;
    }
}

// ---------------- LSTM aggregation ----------------
// grid 1250 (e = bx&1, 625 node-groups of 32 per e), block 1024 (16 waves).
// MFMA 32x32x16, v6 structure. Changes vs v6:
//  - x gather reg-staged 2 steps ahead (1 dwordx2/lane; 2 parity reg sets, no
//    reg moves -> no forced vmcnt waits); swizzle applied at ds_write.
//  - per-step barrier = lgkmcnt(0)+s_barrier only; in-flight x loads cross it.
//  - h output captured in hfin regs (cndmask), stored once after the loop.
__global__ __launch_bounds__(1024, 4)
void k_lstm(const h16* __restrict__ src, const int* __restrict__ nbr_g,
            const int* __restrict__ deg_g, const h16* __restrict__ Bp_g,
            const float* __restrict__ bias_g, const int* __restrict__ perm_g,
            h16* __restrict__ out_g) {
    const int bx = blockIdx.x;
    const int e = bx & 1;
    const int node0 = (bx >> 1) * 32;
    const int* nbr  = nbr_g  + (size_t)e * NN * DD;
    const int* deg  = deg_g  + (size_t)e * NN;
    const int* perm = perm_g + (size_t)e * NN;
    const h16* Bp   = Bp_g + (size_t)e * 131072u;
    const float* bias = bias_g + e * GG;
    h16* outp = out_g + (size_t)e * NN * FF;

    __shared__ unsigned short Axb[2][32 * 128];   // x_t tiles (swizzled, dbuf)
    __shared__ unsigned short Ahb[2][32 * 128];   // h tiles (swizzled, dbuf)
    __shared__ int nbr_l[32 * DD];

    const int tid = threadIdx.x;
    const int l = tid & 63, w = tid >> 6;          // 16 waves
    const int hi = l >> 5, col = l & 31;

    // stage neighbor lists (512 ints)
    if (tid < 512) {
        int node = node0 + (tid >> 4);
        nbr_l[tid] = nbr[(size_t)perm[node] * DD + (tid & 15)];
    }
    // zero Ahb[0] (8KB / 1024 thr = 8B each)
    *(uint2*)&Ahb[0][tid * 4] = make_uint2(0, 0);

    const int pn    = perm[node0 + col];
    const int degl  = deg[pn];
    const int tmax  = deg[perm[node0]];

    float biasr[16];
#pragma unroll
    for (int r = 0; r < 16; r++)
        biasr[r] = bias[(r >> 2) * 128 + w * 8 + (r & 3) + 4 * hi];

    // preload this wave's A-fragments (weights): 16 x half8 = 64 VGPR
    half8 breg[16];
#pragma unroll
    for (int kc = 0; kc < 16; kc++)
        breg[kc] = *(const half8*)(Bp + ((size_t)(w * 16 + kc) * 64 + l) * 8);

    float cst[4] = {0.f, 0.f, 0.f, 0.f};
    uint2 hfin = make_uint2(0, 0);                // deg==0 nodes -> zeros

    // x gather: wave w owns tile rows {2w, 2w+1}; lane covers 8B of one row.
    const int grow  = 2 * w + hi;
    const int gcolb = (l & 31) * 8;
    const int xwoff = grow * 256 + (gcolb ^ ((grow & 15) << 4));   // swizzled ds_write

    auto gload = [&](int t1) -> uint2 {
        int idx = nbr_l[grow * DD + t1];
        return *(const uint2*)((const char*)src + (size_t)idx * 256 + gcolb);
    };

    BAR();                            // nbr_l + Ahb[0] zeros visible

    uint2 xr0 = gload(0);
    uint2 xA  = gload(tmax > 1 ? 1 : 0);          // x(1) (clamped)
    *(uint2*)((char*)Axb[0] + xwoff) = xr0;       // auto vmcnt wait on xr0 only
    BAR();                            // Axb[0] ready; xA still in flight

    uint2 xB;
    auto STEP = [&](int t, uint2& xpend, uint2& xfly) {
        const int cur = t & 1, nxt = cur ^ 1;
        // issue x(t+2) load (stays in flight across the barrier)
        xfly = gload(t + 2 < DD ? t + 2 : DD - 1);

        f32x16 acc;
#pragma unroll
        for (int r = 0; r < 16; r++) acc[r] = biasr[r];
#pragma unroll
        for (int kc = 0; kc < 16; kc++) {
            const char* S = (kc < 8) ? (const char*)Axb[cur] : (const char*)Ahb[cur];
            int ko = (kc & 7) * 32 + hi * 16;
            half8 bf = *(const half8*)(S + col * 256 + (ko ^ ((col & 15) << 4)));
            acc = __builtin_amdgcn_mfma_f32_32x32x16_f16(breg[kc], bf, acc, 0, 0, 0);
        }

        // in-lane cell update for 4 (node,feat) cells
        unsigned short hq[4];
#pragma unroll
        for (int q = 0; q < 4; q++) {
            float iv = sigm(acc[q]);
            float fv = sigm(acc[4 + q]);
            float gv = tanh_(acc[8 + q]);
            float ov = sigm(acc[12 + q]);
            float c_ = fv * cst[q] + iv * gv;
            float h_ = ov * tanh_(c_);
            cst[q] = c_;
            hq[q] = __builtin_bit_cast(unsigned short, (h16)h_);
        }
        uint2 hv;
        hv.x = (unsigned int)hq[0] | ((unsigned int)hq[1] << 16);
        hv.y = (unsigned int)hq[2] | ((unsigned int)hq[3] << 16);

        bool fire = (t + 1 == degl);
        hfin.x = fire ? hv.x : hfin.x;
        hfin.y = fire ? hv.y : hfin.y;

        // write h(t+1) and x(t+1) into the nxt buffers
        int ho = (w * 16 + 8 * hi) ^ ((col & 15) << 4);
        *(uint2*)((char*)Ahb[nxt] + col * 256 + ho) = hv;
        *(uint2*)((char*)Axb[nxt] + xwoff) = xpend;   // auto vmcnt wait on xpend only

        BAR();                       // LDS visible; xfly stays in flight
    };

#pragma unroll 1
    for (int t = 0; t < tmax; t += 2) {
        STEP(t, xA, xB);
        if (t + 1 < tmax) STEP(t + 1, xB, xA);
    }

    *(uint2*)&outp[(size_t)pn * FF + w * 8 + 4 * hi] = hfin;
}

// ---------------- layer-1 combine: h1 = relu([x|n0|n1] @ Wcat1 + bs1) ----------------
__global__ __launch_bounds__(256, 4)
void k_lout1(const h16* __restrict__ x16, const h16* __restrict__ n0,
             const h16* __restrict__ n1, const h16* __restrict__ Cp,
             const float* __restrict__ bs, h16* __restrict__ h1) {
    __shared__ unsigned short A3[3][64 * 128];
    const int tid = threadIdx.x;
    const int l = tid & 63, w = tid >> 6, lg = l >> 4, ll = l & 15;
    const int node0 = blockIdx.x * 64;
    const h16* srcs[3] = {x16, n0, n1};
#pragma unroll
    for (int r3 = 0; r3 < 3; r3++)
#pragma unroll
        for (int k = 0; k < 4; k++) {
            int row = w * 16 + k * 4 + lg;
            int node = node0 + row;
            uint4 v = (node < NN) ? *(const uint4*)(srcs[r3] + (size_t)node * FF + ll * 8)
                                  : make_uint4(0, 0, 0, 0);
            *(uint4*)((char*)&A3[r3][0] + row * 256 + ((ll * 16) ^ ((row & 7) << 4))) = v;
        }
    __syncthreads();

    f32x4 acc[4][2];
#pragma unroll
    for (int rt = 0; rt < 4; rt++)
#pragma unroll
        for (int ct = 0; ct < 2; ct++) {
            float b = bs[(w * 2 + ct) * 16 + ll];
            acc[rt][ct] = (f32x4){b, b, b, b};
        }
#pragma unroll
    for (int kc = 0; kc < 12; kc++) {
        const unsigned short* Asrc = &A3[kc >> 2][0];
        int kcL = kc & 3;
        half8 af[4];
#pragma unroll
        for (int rt = 0; rt < 4; rt++) af[rt] = load_afrag16(Asrc, rt * 16, ll, lg, kcL);
        half8 bf[2];
#pragma unroll
        for (int ct = 0; ct < 2; ct++)
            bf[ct] = *(const half8*)(Cp + ((size_t)(kc * 8 + w * 2 + ct) * 64 + l) * 8);
#pragma unroll
        for (int rt = 0; rt < 4; rt++)
#pragma unroll
            for (int ct = 0; ct < 2; ct++)
                acc[rt][ct] = __builtin_amdgcn_mfma_f32_16x16x32_f16(af[rt], bf[ct], acc[rt][ct], 0, 0, 0);
    }
#pragma unroll
    for (int rt = 0; rt < 4; rt++)
#pragma unroll
        for (int ct = 0; ct < 2; ct++)
#pragma unroll
            for (int r = 0; r < 4; r++) {
                int node = node0 + rt * 16 + (lg << 2) + r;
                if (node < NN) {
                    float v = acc[rt][ct][r];
                    v = v > 0.f ? v : 0.f;
                    h1[(size_t)node * FF + (w * 2 + ct) * 16 + ll] = (h16)v;
                }
            }
}

// ---------------- layer-2 combine + softmax (C=2) ----------------
__global__ void k_lout2(const h16* __restrict__ h1, const h16* __restrict__ n0,
                        const h16* __restrict__ n1, const float* __restrict__ wc2,
                        const float* __restrict__ b2s, float* __restrict__ out) {
    __shared__ float Wl[768];
    const int tid = threadIdx.x;
    for (int i = tid; i < 768; i += 256) Wl[i] = wc2[i];
    __syncthreads();
    const int node = blockIdx.x * 64 + (tid >> 2);
    const int q = tid & 3;
    float a0 = 0.f, a1 = 0.f;
    if (node < NN) {
        const h16* srcs[3] = {h1, n0, n1};
#pragma unroll
        for (int r3 = 0; r3 < 3; r3++) {
            const h16* sp = srcs[r3] + (size_t)node * FF + q * 32;
#pragma unroll
            for (int c4 = 0; c4 < 4; c4++) {
                half8 v = *(const half8*)(sp + c4 * 8);
#pragma unroll
                for (int i = 0; i < 8; i++) {
                    float xv = (float)v[i];
                    int k = r3 * 128 + q * 32 + c4 * 8 + i;
                    a0 += xv * Wl[k * 2];
                    a1 += xv * Wl[k * 2 + 1];
                }
            }
        }
    }
    a0 += __shfl_xor(a0, 1); a0 += __shfl_xor(a0, 2);
    a1 += __shfl_xor(a1, 1); a1 += __shfl_xor(a1, 2);
    if (q == 0 && node < NN) {
        a0 += b2s[0]; a1 += b2s[1];
        out[(size_t)node * 2]     = a0;
        out[(size_t)node * 2 + 1] = a1;
        float m = fmaxf(a0, a1);
        float e0 = __expf(a0 - m), e1 = __expf(a1 - m);
        float s = 1.f / (e0 + e1);
        out[40000 + (size_t)node * 2]     = e0 * s;
        out[40000 + (size_t)node * 2 + 1] = e1 * s;
    }
}

extern "C" void kernel_launch(void* const* d_in, const int* in_sizes, int n_in,
                              void* d_out, int out_size, void* d_ws, size_t ws_size,
                              hipStream_t stream) {
    const float* x     = (const float*)d_in[0];
    const int*   nbr   = (const int*)d_in[1];
    const int*   deg   = (const int*)d_in[2];
    const float* l1Wih = (const float*)d_in[3];
    const float* l1Whh = (const float*)d_in[4];
    const float* l1bih = (const float*)d_in[5];
    const float* l1bhh = (const float*)d_in[6];
    const float* l1Ws  = (const float*)d_in[7];
    const float* l1Wn  = (const float*)d_in[8];
    const float* l1b   = (const float*)d_in[9];
    const float* l2Wih = (const float*)d_in[10];
    const float* l2Whh = (const float*)d_in[11];
    const float* l2bih = (const float*)d_in[12];
    const float* l2bhh = (const float*)d_in[13];
    const float* l2Ws  = (const float*)d_in[14];
    const float* l2Wn  = (const float*)d_in[15];
    const float* l2b   = (const float*)d_in[16];

    char* ws = (char*)d_ws;
    h16*  x16   = (h16*)(ws + OFF_X);
    h16*  h1    = (h16*)(ws + OFF_H1);
    h16*  n1b   = (h16*)(ws + OFF_N1);
    h16*  n2b   = (h16*)(ws + OFF_N2);
    h16*  B1    = (h16*)(ws + OFF_B1);                 // sets 0,1 (layer1 e0,e1)
    h16*  B2    = (h16*)(ws + OFF_B1) + 2u * 131072u;  // sets 2,3 (layer2 e0,e1)
    h16*  Cp1   = (h16*)(ws + OFF_WC1);
    float* wc2  = (float*)(ws + OFF_WC2);
    float* bias1 = (float*)(ws + OFF_BI1);
    float* bias2 = (float*)(ws + OFF_BI2);
    float* bs1   = (float*)(ws + OFF_BS1);
    float* b2s   = (float*)(ws + OFF_B2S);
    int*   perm  = (int*)(ws + OFF_PERM);
    int*   hist  = (int*)(ws + OFF_HIST);
    int*   cur   = (int*)(ws + OFF_CUR);

    hipMemsetAsync(hist, 0, 256, stream);              // zero 2x32 histogram
    k_prep<<<dim3(1696), dim3(256), 0, stream>>>(x, x16,
                                                 l1Wih, l1Whh, l2Wih, l2Whh, B1,
                                                 l1Ws, l1Wn, Cp1,
                                                 l1bih, l1bhh, l2bih, l2bhh,
                                                 l1b, l2Ws, l2Wn, l2b,
                                                 bias1, bias2, bs1, wc2, b2s,
                                                 deg, hist);
    k_scan   <<<dim3(1),     dim3(64),  0, stream>>>(hist, cur);
    k_scatter<<<dim3(79, 2), dim3(256), 0, stream>>>(deg, cur, perm);

    k_lstm <<<dim3(1250), dim3(1024), 0, stream>>>(x16, nbr, deg, B1, bias1, perm, n1b);
    k_lout1<<<dim3(313),  dim3(256),  0, stream>>>(x16, n1b, n1b + (size_t)NN * FF, Cp1, bs1, h1);
    k_lstm <<<dim3(1250), dim3(1024), 0, stream>>>(h1, nbr, deg, B2, bias2, perm, n2b);
    k_lout2<<<dim3(313),  dim3(256),  0, stream>>>(h1, n2b, n2b + (size_t)NN * FF, wc2, b2s,
                                                   (float*)d_out);
}

// Round 10
// 436.577 us; speedup vs baseline: 2.0971x; 2.0971x over previous
//
#include <hip/hip_runtime.h>
#include <stdint.h>

#define NN 20000
#define DD 16
#define FF 128
#define GG 512   // 4*F

typedef _Float16 h16;
typedef _Float16 half8 __attribute__((ext_vector_type(8)));
typedef float f32x4 __attribute__((ext_vector_type(4)));
typedef float f32x16 __attribute__((ext_vector_type(16)));

// ---- workspace layout (bytes, all 256-aligned) ----
#define OFF_X    0u          // x_f16   [N][128]          5,120,000
#define OFF_H1   5120000u    // h1_f16  [N][128]          5,120,000
#define OFF_N1   10240000u   // n1buf   [2][N][128] f16  10,240,000
#define OFF_N2   20480000u   // n2buf   [2][N][128] f16  10,240,000
#define OFF_B1   30720000u   // Bpack   [4sets][16w][16kc][64lane][8] f16 (1MB)
#define OFF_WC1  31768576u   // Cpack   [12][8][64][8] f16
#define OFF_WC2  31866880u   // Wcat2   [384][2] f32
#define OFF_BI1  31869952u   // bias1   [2][512] f32
#define OFF_BI2  31874048u   // bias2   [2][512] f32
#define OFF_BS1  31878144u   // bs1     [128] f32
#define OFF_B2S  31878656u   // b2s     [2] f32
#define OFF_PERM 31878912u   // perm    [2][N] int32       160,000
#define OFF_HIST 32039168u   // hist    [2][32] int32
#define OFF_CUR  32039424u   // cursor  [2][32] int32

__device__ __forceinline__ float sigm(float x)  { return __builtin_amdgcn_rcpf(1.f + __expf(-x)); }
__device__ __forceinline__ float tanh_(float x) { return 2.f * __builtin_amdgcn_rcpf(1.f + __expf(-2.f * x)) - 1.f; }

__device__ __forceinline__ void gload_lds16(const void* g, void* s) {
    __builtin_amdgcn_global_load_lds((const __attribute__((address_space(1))) void*)g,
                                     (__attribute__((address_space(3))) void*)s, 16, 0, 0);
}

// 16x16x32 A-fragment loader (k_lout1 only), [64][128] tile, (row&7)<<4 swizzle
__device__ __forceinline__ half8 load_afrag16(const unsigned short* Asrc, int rowbase,
                                              int ll, int lg, int kcL) {
    int row = rowbase + ll;
    int o = (kcL * 64 + lg * 16) ^ ((row & 7) << 4);
    return *(const half8*)((const char*)Asrc + row * 256 + o);
}

// ---------------- fused prep kernel ----------------
// grid 1696 x 256: [0,1250) cast_x | [1250,1506) pack_gates | [1506,1530) pack_wc1
// | [1530,1538) small (biases, wc2) | [1538,1696) degree histogram
// (hist zeroed by hipMemsetAsync before this kernel)
__global__ void k_prep(const float* __restrict__ x, h16* __restrict__ xo,
                       const float* __restrict__ l1Wih, const float* __restrict__ l1Whh,
                       const float* __restrict__ l2Wih, const float* __restrict__ l2Whh,
                       h16* __restrict__ Bp,
                       const float* __restrict__ l1Ws, const float* __restrict__ l1Wn,
                       h16* __restrict__ Cp,
                       const float* __restrict__ l1bih, const float* __restrict__ l1bhh,
                       const float* __restrict__ l2bih, const float* __restrict__ l2bhh,
                       const float* __restrict__ l1b,  const float* __restrict__ l2Ws,
                       const float* __restrict__ l2Wn, const float* __restrict__ l2b,
                       float* __restrict__ bias1, float* __restrict__ bias2,
                       float* __restrict__ bs1,  float* __restrict__ wc2,
                       float* __restrict__ b2s,
                       const int* __restrict__ deg, int* __restrict__ hist) {
    const int b = blockIdx.x, tid = threadIdx.x;
    if (b < 1250) {
        int base = (b * 256 + tid) * 8;
        const float4* p = (const float4*)(x + base);
        float4 a = p[0], c = p[1];
        half8 v = {(h16)a.x,(h16)a.y,(h16)a.z,(h16)a.w,(h16)c.x,(h16)c.y,(h16)c.z,(h16)c.w};
        *(half8*)(xo + base) = v;
    } else if (b < 1506) {
        int idx = (b - 1250) * 256 + tid;
        int set = idx >> 14;
        int rem = idx & 16383;
        int w   = rem >> 10;
        int kc  = (rem >> 6) & 15;
        int l   = rem & 63;
        const float* Wih = (set < 2 ? l1Wih : l2Wih) + (size_t)(set & 1) * (FF * GG);
        const float* Whh = (set < 2 ? l1Whh : l2Whh) + (size_t)(set & 1) * (FF * GG);
        int rl   = l & 31;
        int gate = rl >> 3, fl = rl & 7;
        int col  = gate * 128 + w * 8 + fl;
        int hi   = l >> 5;
        half8 v;
#pragma unroll
        for (int j = 0; j < 8; j++) {
            int k = kc * 16 + 8 * hi + j;
            float val = (k < FF) ? Wih[k * GG + col] : Whh[(k - FF) * GG + col];
            v[j] = (h16)val;
        }
        *(half8*)(Bp + (size_t)idx * 8) = v;
    } else if (b < 1530) {
        int idx = (b - 1506) * 256 + tid;
        int kc = idx >> 9;
        int ct = (idx >> 6) & 7;
        int l  = idx & 63;
        int col = ct * 16 + (l & 15);
        half8 v;
#pragma unroll
        for (int j = 0; j < 8; j++) {
            int k = kc * 32 + ((l >> 4) << 3) + j;
            float val;
            if (k < 128)      val = 0.5f * (l1Ws[k * 128 + col] + l1Ws[16384 + k * 128 + col]);
            else if (k < 256) val = 0.5f * l1Wn[(k - 128) * 128 + col];
            else              val = 0.5f * l1Wn[16384 + (k - 256) * 128 + col];
            v[j] = (h16)val;
        }
        *(half8*)(Cp + (size_t)idx * 8) = v;
    } else if (b < 1538) {
        int g = (b - 1530) * 256 + tid;
        if (g < 1024) bias1[g] = l1bih[g] + l1bhh[g];
        else if (g < 2048) { int j = g - 1024; bias2[j] = l2bih[j] + l2bhh[j]; }
        if (g < 128) bs1[g] = 0.5f * (l1b[g] + l1b[128 + g]);
        if (g < 768) {
            int k = g >> 1, c = g & 1;
            float val;
            if (k < 128)      val = 0.5f * (l2Ws[k * 2 + c] + l2Ws[256 + k * 2 + c]);
            else if (k < 256) val = 0.5f * l2Wn[(k - 128) * 2 + c];
            else              val = 0.5f * l2Wn[256 + (k - 256) * 2 + c];
            wc2[g] = val;
        }
        if (g < 2) b2s[g] = 0.5f * (l2b[g] + l2b[2 + g]);
    } else {
        int bb = b - 1538;               // 0..157, 79 blocks per e
        int e = bb / 79;
        int n = (bb % 79) * 256 + tid;
        if (n < NN) atomicAdd(&hist[e * 32 + deg[(size_t)e * NN + n]], 1);
    }
}

// ---------------- degree sort (descending, counting sort) ----------------
__global__ void k_scan(const int* __restrict__ hist, int* __restrict__ cursor) {
    int e = threadIdx.x;
    if (e < 2) {
        int acc = 0;
        for (int d = 16; d >= 0; d--) { cursor[e * 32 + d] = acc; acc += hist[e * 32 + d]; }
    }
}
__global__ void k_scatter(const int* __restrict__ deg, int* __restrict__ cursor,
                          int* __restrict__ perm) {
    int e = blockIdx.y; int n = blockIdx.x * 256 + threadIdx.x;
    if (n < NN) {
        int d = deg[(size_t)e * NN + n];
        int p = atomicAdd(&cursor[e * 32 + d], 1);
        perm[(size_t)e * NN + p] = n;
    }
}

// ---------------- LSTM aggregation ----------------
// grid 1250 (e = bx&1, 625 node-groups of 32 per e), block 1024 (16 waves).
// v6-proven structure (117 us, WRITE=10MB no-spill). MFMA 32x32x16: A = weight
// rows (wave w owns feats w*8..+7, breg[16]=64 regs in AGPR-side), B = 32
// node-cols from swizzled LDS tile; lane holds i,f,g,o of 4 cells in-lane.
// Degree-sorted; one barrier per step; async gather (global_load_lds) 1 ahead.
// Only change vs v6: s_setprio(1/0) around the MFMA cluster (4 blocks/CU at
// different t-phases -> scheduler can favor MFMA-entering waves, T5 regime).
__global__ __launch_bounds__(1024, 4)
void k_lstm(const h16* __restrict__ src, const int* __restrict__ nbr_g,
            const int* __restrict__ deg_g, const h16* __restrict__ Bp_g,
            const float* __restrict__ bias_g, const int* __restrict__ perm_g,
            h16* __restrict__ out_g) {
    const int bx = blockIdx.x;
    const int e = bx & 1;
    const int node0 = (bx >> 1) * 32;
    const int* nbr  = nbr_g  + (size_t)e * NN * DD;
    const int* deg  = deg_g  + (size_t)e * NN;
    const int* perm = perm_g + (size_t)e * NN;
    const h16* Bp   = Bp_g + (size_t)e * 131072u;
    const float* bias = bias_g + e * GG;
    h16* outp = out_g + (size_t)e * NN * FF;

    __shared__ unsigned short Axb[2][32 * 128];   // x_t tiles (swizzled, dbuf)
    __shared__ unsigned short Ahb[2][32 * 128];   // h tiles (swizzled, dbuf)
    __shared__ int nbr_l[32 * DD];

    const int tid = threadIdx.x;
    const int l = tid & 63, w = tid >> 6;          // 16 waves
    const int hi = l >> 5, col = l & 31;

    // stage neighbor lists (512 ints)
    if (tid < 512) {
        int node = node0 + (tid >> 4);
        nbr_l[tid] = nbr[(size_t)perm[node] * DD + (tid & 15)];
    }
    // zero Ahb[0] (8KB / 1024 thr = 8B each)
    *(uint2*)&Ahb[0][tid * 4] = make_uint2(0, 0);

    const int pn    = perm[node0 + col];
    const int degl  = deg[pn];
    const int tmax  = deg[perm[node0]];

    float biasr[16];
#pragma unroll
    for (int r = 0; r < 16; r++)
        biasr[r] = bias[(r >> 2) * 128 + w * 8 + (r & 3) + 4 * hi];

    if (degl == 0)
        *(uint2*)&outp[(size_t)pn * FF + w * 8 + 4 * hi] = make_uint2(0, 0);

    // preload this wave's A-fragments (weights): 16 x half8 = 64 regs
    half8 breg[16];
#pragma unroll
    for (int kc = 0; kc < 16; kc++)
        breg[kc] = *(const half8*)(Bp + ((size_t)(w * 16 + kc) * 64 + l) * 8);

    float cst[4] = {0.f, 0.f, 0.f, 0.f};

    // async gather: waves 0-7, 1 instr each covers 4 rows (64 lanes x 16B).
    // LDS dest linear; swizzle via XOR-permuted per-lane GLOBAL source slot.
    auto do_gather = [&](int t1, unsigned short* dst) {
        if (w < 8) {
            int row = w * 4 + (l >> 4);
            int idx = nbr_l[row * DD + t1];
            const char* gp = (const char*)(src + (size_t)idx * FF)
                             + (((l & 15) * 16) ^ ((row & 15) << 4));
            gload_lds16(gp, &dst[(w * 4) * 128]);
        }
    };

    __syncthreads();                 // nbr_l + Ahb[0] zeros visible
    do_gather(0, Axb[0]);
    __syncthreads();                 // vmcnt drain -> Axb[0] ready

#pragma unroll 1
    for (int t = 0; t < tmax; t++) {
        const int cur = t & 1, nxt = cur ^ 1;
        if (t + 1 < tmax) do_gather(t + 1, Axb[nxt]);   // full step to hide

        f32x16 acc;
#pragma unroll
        for (int r = 0; r < 16; r++) acc[r] = biasr[r];

        __builtin_amdgcn_s_setprio(1);
#pragma unroll
        for (int kc = 0; kc < 16; kc++) {
            const unsigned short* S = (kc < 8) ? Axb[cur] : Ahb[cur];
            int ko = (kc & 7) * 32 + hi * 16;
            half8 bf = *(const half8*)((const char*)S + col * 256
                                       + (ko ^ ((col & 15) << 4)));
            acc = __builtin_amdgcn_mfma_f32_32x32x16_f16(breg[kc], bf, acc, 0, 0, 0);
        }
        __builtin_amdgcn_s_setprio(0);

        // in-lane cell update for 4 (node,feat) cells
        unsigned int hlo, hhi2;
        {
            unsigned short hq[4];
#pragma unroll
            for (int q = 0; q < 4; q++) {
                float iv = sigm(acc[q]);
                float fv = sigm(acc[4 + q]);
                float gv = tanh_(acc[8 + q]);
                float ov = sigm(acc[12 + q]);
                float c_ = fv * cst[q] + iv * gv;
                float h_ = ov * tanh_(c_);
                cst[q] = c_;
                h16 hh = (h16)h_;
                hq[q] = __builtin_bit_cast(unsigned short, hh);
            }
            hlo  = (unsigned int)hq[0] | ((unsigned int)hq[1] << 16);
            hhi2 = (unsigned int)hq[2] | ((unsigned int)hq[3] << 16);
        }
        // write h into Ahb[nxt] (readers crossed barrier at end of t-1)
        {
            int ho = (w * 16 + 8 * hi) ^ ((col & 15) << 4);
            *(uint2*)((char*)Ahb[nxt] + col * 256 + ho) = make_uint2(hlo, hhi2);
        }
        if (t + 1 == degl)
            *(uint2*)&outp[(size_t)pn * FF + w * 8 + 4 * hi] = make_uint2(hlo, hhi2);

        __syncthreads();   // one barrier: Ah[nxt] + gathered Ax[nxt] visible
    }
}

// ---------------- layer-1 combine: h1 = relu([x|n0|n1] @ Wcat1 + bs1) ----------------
__global__ __launch_bounds__(256, 4)
void k_lout1(const h16* __restrict__ x16, const h16* __restrict__ n0,
             const h16* __restrict__ n1, const h16* __restrict__ Cp,
             const float* __restrict__ bs, h16* __restrict__ h1) {
    __shared__ unsigned short A3[3][64 * 128];
    const int tid = threadIdx.x;
    const int l = tid & 63, w = tid >> 6, lg = l >> 4, ll = l & 15;
    const int node0 = blockIdx.x * 64;
    const h16* srcs[3] = {x16, n0, n1};
#pragma unroll
    for (int r3 = 0; r3 < 3; r3++)
#pragma unroll
        for (int k = 0; k < 4; k++) {
            int row = w * 16 + k * 4 + lg;
            int node = node0 + row;
            uint4 v = (node < NN) ? *(const uint4*)(srcs[r3] + (size_t)node * FF + ll * 8)
                                  : make_uint4(0, 0, 0, 0);
            *(uint4*)((char*)&A3[r3][0] + row * 256 + ((ll * 16) ^ ((row & 7) << 4))) = v;
        }
    __syncthreads();

    f32x4 acc[4][2];
#pragma unroll
    for (int rt = 0; rt < 4; rt++)
#pragma unroll
        for (int ct = 0; ct < 2; ct++) {
            float b = bs[(w * 2 + ct) * 16 + ll];
            acc[rt][ct] = (f32x4){b, b, b, b};
        }
#pragma unroll
    for (int kc = 0; kc < 12; kc++) {
        const unsigned short* Asrc = &A3[kc >> 2][0];
        int kcL = kc & 3;
        half8 af[4];
#pragma unroll
        for (int rt = 0; rt < 4; rt++) af[rt] = load_afrag16(Asrc, rt * 16, ll, lg, kcL);
        half8 bf[2];
#pragma unroll
        for (int ct = 0; ct < 2; ct++)
            bf[ct] = *(const half8*)(Cp + ((size_t)(kc * 8 + w * 2 + ct) * 64 + l) * 8);
#pragma unroll
        for (int rt = 0; rt < 4; rt++)
#pragma unroll
            for (int ct = 0; ct < 2; ct++)
                acc[rt][ct] = __builtin_amdgcn_mfma_f32_16x16x32_f16(af[rt], bf[ct], acc[rt][ct], 0, 0, 0);
    }
#pragma unroll
    for (int rt = 0; rt < 4; rt++)
#pragma unroll
        for (int ct = 0; ct < 2; ct++)
#pragma unroll
            for (int r = 0; r < 4; r++) {
                int node = node0 + rt * 16 + (lg << 2) + r;
                if (node < NN) {
                    float v = acc[rt][ct][r];
                    v = v > 0.f ? v : 0.f;
                    h1[(size_t)node * FF + (w * 2 + ct) * 16 + ll] = (h16)v;
                }
            }
}

// ---------------- layer-2 combine + softmax (C=2) ----------------
__global__ void k_lout2(const h16* __restrict__ h1, const h16* __restrict__ n0,
                        const h16* __restrict__ n1, const float* __restrict__ wc2,
                        const float* __restrict__ b2s, float* __restrict__ out) {
    __shared__ float Wl[768];
    const int tid = threadIdx.x;
    for (int i = tid; i < 768; i += 256) Wl[i] = wc2[i];
    __syncthreads();
    const int node = blockIdx.x * 64 + (tid >> 2);
    const int q = tid & 3;
    float a0 = 0.f, a1 = 0.f;
    if (node < NN) {
        const h16* srcs[3] = {h1, n0, n1};
#pragma unroll
        for (int r3 = 0; r3 < 3; r3++) {
            const h16* sp = srcs[r3] + (size_t)node * FF + q * 32;
#pragma unroll
            for (int c4 = 0; c4 < 4; c4++) {
                half8 v = *(const half8*)(sp + c4 * 8);
#pragma unroll
                for (int i = 0; i < 8; i++) {
                    float xv = (float)v[i];
                    int k = r3 * 128 + q * 32 + c4 * 8 + i;
                    a0 += xv * Wl[k * 2];
                    a1 += xv * Wl[k * 2 + 1];
                }
            }
        }
    }
    a0 += __shfl_xor(a0, 1); a0 += __shfl_xor(a0, 2);
    a1 += __shfl_xor(a1, 1); a1 += __shfl_xor(a1, 2);
    if (q == 0 && node < NN) {
        a0 += b2s[0]; a1 += b2s[1];
        out[(size_t)node * 2]     = a0;
        out[(size_t)node * 2 + 1] = a1;
        float m = fmaxf(a0, a1);
        float e0 = __expf(a0 - m), e1 = __expf(a1 - m);
        float s = 1.f / (e0 + e1);
        out[40000 + (size_t)node * 2]     = e0 * s;
        out[40000 + (size_t)node * 2 + 1] = e1 * s;
    }
}

extern "C" void kernel_launch(void* const* d_in, const int* in_sizes, int n_in,
                              void* d_out, int out_size, void* d_ws, size_t ws_size,
                              hipStream_t stream) {
    const float* x     = (const float*)d_in[0];
    const int*   nbr   = (const int*)d_in[1];
    const int*   deg   = (const int*)d_in[2];
    const float* l1Wih = (const float*)d_in[3];
    const float* l1Whh = (const float*)d_in[4];
    const float* l1bih = (const float*)d_in[5];
    const float* l1bhh = (const float*)d_in[6];
    const float* l1Ws  = (const float*)d_in[7];
    const float* l1Wn  = (const float*)d_in[8];
    const float* l1b   = (const float*)d_in[9];
    const float* l2Wih = (const float*)d_in[10];
    const float* l2Whh = (const float*)d_in[11];
    const float* l2bih = (const float*)d_in[12];
    const float* l2bhh = (const float*)d_in[13];
    const float* l2Ws  = (const float*)d_in[14];
    const float* l2Wn  = (const float*)d_in[15];
    const float* l2b   = (const float*)d_in[16];

    char* ws = (char*)d_ws;
    h16*  x16   = (h16*)(ws + OFF_X);
    h16*  h1    = (h16*)(ws + OFF_H1);
    h16*  n1b   = (h16*)(ws + OFF_N1);
    h16*  n2b   = (h16*)(ws + OFF_N2);
    h16*  B1    = (h16*)(ws + OFF_B1);                 // sets 0,1 (layer1 e0,e1)
    h16*  B2    = (h16*)(ws + OFF_B1) + 2u * 131072u;  // sets 2,3 (layer2 e0,e1)
    h16*  Cp1   = (h16*)(ws + OFF_WC1);
    float* wc2  = (float*)(ws + OFF_WC2);
    float* bias1 = (float*)(ws + OFF_BI1);
    float* bias2 = (float*)(ws + OFF_BI2);
    float* bs1   = (float*)(ws + OFF_BS1);
    float* b2s   = (float*)(ws + OFF_B2S);
    int*   perm  = (int*)(ws + OFF_PERM);
    int*   hist  = (int*)(ws + OFF_HIST);
    int*   cur   = (int*)(ws + OFF_CUR);

    hipMemsetAsync(hist, 0, 256, stream);              // zero 2x32 histogram
    k_prep<<<dim3(1696), dim3(256), 0, stream>>>(x, x16,
                                                 l1Wih, l1Whh, l2Wih, l2Whh, B1,
                                                 l1Ws, l1Wn, Cp1,
                                                 l1bih, l1bhh, l2bih, l2bhh,
                                                 l1b, l2Ws, l2Wn, l2b,
                                                 bias1, bias2, bs1, wc2, b2s,
                                                 deg, hist);
    k_scan   <<<dim3(1),     dim3(64),  0, stream>>>(hist, cur);
    k_scatter<<<dim3(79, 2), dim3(256), 0, stream>>>(deg, cur, perm);

    k_lstm <<<dim3(1250), dim3(1024), 0, stream>>>(x16, nbr, deg, B1, bias1, perm, n1b);
    k_lout1<<<dim3(313),  dim3(256),  0, stream>>>(x16, n1b, n1b + (size_t)NN * FF, Cp1, bs1, h1);
    k_lstm <<<dim3(1250), dim3(1024), 0, stream>>>(h1, nbr, deg, B2, bias2, perm, n2b);
    k_lout2<<<dim3(313),  dim3(256),  0, stream>>>(h1, n2b, n2b + (size_t)NN * FF, wc2, b2s,
                                                   (float*)d_out);
}